// Round 4
// baseline (82.284 us; speedup 1.0000x reference)
//
#include <hip/hip_runtime.h>

#define Bn 16
#define Qn 128
#define Kn 128
#define Dn 512
#define Hn 512
#define NEGV (-3.0e38f)
// 2*log2(e): exp2(PSCALE*x) == e^{2x}
#define PSCALE 2.8853900817779268f

typedef short s16x8 __attribute__((ext_vector_type(8)));
typedef float f32x4 __attribute__((ext_vector_type(4)));

__device__ __forceinline__ float exp2_hw(float x) {
  float r;
  asm("v_exp_f32 %0, %1" : "=v"(r) : "v"(x));
  return r;
}
__device__ __forceinline__ unsigned short f2bf(float f) {   // RNE f32->bf16
  unsigned int u = __float_as_uint(f);
  u += 0x7fff + ((u >> 16) & 1);
  return (unsigned short)(u >> 16);
}

// ---------- K1: convert inputs to bf16 (A rows, W transposed, V transposed) ----------
__global__ __launch_bounds__(256) void convert_kernel(
    const float* __restrict__ queries, const float* __restrict__ keys,
    const float* __restrict__ Wq, const float* __restrict__ Wk,
    const float* __restrict__ values,
    unsigned short* __restrict__ Abf, unsigned short* __restrict__ Wt,
    unsigned short* __restrict__ Vt)
{
  const int bid = blockIdx.x, t = threadIdx.x;
  if (bid < 512) {
    const int gid = bid * 256 + t;
    const size_t base = (size_t)gid * 16;
    const float* src = (base < 1048576) ? (queries + base) : (keys + (base - 1048576));
    unsigned short o[16];
    #pragma unroll
    for (int j = 0; j < 4; ++j) {
      float4 v = *(const float4*)(src + j * 4);
      o[j * 4 + 0] = f2bf(v.x); o[j * 4 + 1] = f2bf(v.y);
      o[j * 4 + 2] = f2bf(v.z); o[j * 4 + 3] = f2bf(v.w);
    }
    #pragma unroll
    for (int j = 0; j < 4; ++j)
      *(ushort4*)(Abf + base + j * 4) = *(ushort4*)&o[j * 4];
  } else if (bid < 640) {
    const int tid = (bid - 512) * 256 + t;
    const int n = tid & 511, rest = tid >> 9;
    const int sel = rest >> 5, k16 = rest & 31;
    const float* W = sel ? Wk : Wq;
    unsigned short o[16];
    #pragma unroll
    for (int i = 0; i < 16; ++i)
      o[i] = f2bf(W[(size_t)(k16 * 16 + i) * Hn + n]);
    unsigned short* dst = Wt + (size_t)sel * 262144 + (size_t)n * 512 + k16 * 16;
    #pragma unroll
    for (int j = 0; j < 4; ++j) *(ushort4*)(dst + j * 4) = *(ushort4*)&o[j * 4];
  } else {
    const int tid = (bid - 640) * 256 + t;
    const int d = tid & 511, rest = tid >> 9;
    const int b = rest >> 2, k32 = rest & 3;
    unsigned short o[32];
    #pragma unroll
    for (int i = 0; i < 32; ++i)
      o[i] = f2bf(values[((size_t)(b * Kn + k32 * 32 + i)) * Dn + d]);
    unsigned short* dst = Vt + (size_t)b * 65536 + (size_t)d * 128 + k32 * 32;
    #pragma unroll
    for (int j = 0; j < 8; ++j) *(ushort4*)(dst + j * 4) = *(ushort4*)&o[j * 4];
  }
}

// ---------- K2: projections via bf16 MFMA ----------
// q rows -> QW[q][512 h][{WF=-2*wv*e^{-2q}, F=e^{-2q}}] f32
// k rows -> Ekt[b][256 h2][128 k][{e^{2k}(2h2), e^{2k}(2h2+1)}] f32  (score-LDS layout)
__global__ __launch_bounds__(256) void proj_mfma(
    const unsigned short* __restrict__ Abf, const unsigned short* __restrict__ Wt,
    const float* __restrict__ wv,
    float* __restrict__ QW, float* __restrict__ Ekt)
{
  __shared__ unsigned short Al[128][72];
  __shared__ unsigned short Bl[64][72];
  const int t = threadIdx.x, w = t >> 6, l = t & 63;
  const int wm = w >> 1, wn = w & 1;
  const int rowTile = blockIdx.x;          // 0..31
  const int n0 = blockIdx.y * 64;
  const int R0 = rowTile * 128;
  const bool isQ = rowTile < 16;
  const unsigned short* Wsel = Wt + (isQ ? 0 : 262144);

  f32x4 acc[4][2];
  #pragma unroll
  for (int m = 0; m < 4; ++m)
    #pragma unroll
    for (int n = 0; n < 2; ++n) acc[m][n] = (f32x4)0.f;

  const int lr = l & 15, lk = l >> 4;

  for (int k0 = 0; k0 < Hn; k0 += 64) {
    ushort4 ar[4][2], br[2][2];
    #pragma unroll
    for (int i = 0; i < 4; ++i) {
      int g = t + 256 * i, r = g >> 3, c = g & 7;
      const unsigned short* p = Abf + (size_t)(R0 + r) * Hn + k0 + c * 8;
      ar[i][0] = *(const ushort4*)p; ar[i][1] = *(const ushort4*)(p + 4);
    }
    #pragma unroll
    for (int i = 0; i < 2; ++i) {
      int g = t + 256 * i, r = g >> 3, c = g & 7;
      const unsigned short* p = Wsel + (size_t)(n0 + r) * Hn + k0 + c * 8;
      br[i][0] = *(const ushort4*)p; br[i][1] = *(const ushort4*)(p + 4);
    }
    __syncthreads();
    #pragma unroll
    for (int i = 0; i < 4; ++i) {
      int g = t + 256 * i, r = g >> 3, c = g & 7;
      *(ushort4*)&Al[r][c * 8] = ar[i][0]; *(ushort4*)&Al[r][c * 8 + 4] = ar[i][1];
    }
    #pragma unroll
    for (int i = 0; i < 2; ++i) {
      int g = t + 256 * i, r = g >> 3, c = g & 7;
      *(ushort4*)&Bl[r][c * 8] = br[i][0]; *(ushort4*)&Bl[r][c * 8 + 4] = br[i][1];
    }
    __syncthreads();
    #pragma unroll
    for (int ks = 0; ks < 2; ++ks) {
      s16x8 af[4], bf_[2];
      #pragma unroll
      for (int m = 0; m < 4; ++m)
        af[m] = *(const s16x8*)&Al[wm * 64 + m * 16 + lr][ks * 32 + lk * 8];
      #pragma unroll
      for (int n = 0; n < 2; ++n)
        bf_[n] = *(const s16x8*)&Bl[wn * 32 + n * 16 + lr][ks * 32 + lk * 8];
      #pragma unroll
      for (int m = 0; m < 4; ++m)
        #pragma unroll
        for (int n = 0; n < 2; ++n)
          acc[m][n] = __builtin_amdgcn_mfma_f32_16x16x32_bf16(af[m], bf_[n], acc[m][n], 0, 0, 0);
    }
    __syncthreads();
  }

  #pragma unroll
  for (int m = 0; m < 4; ++m)
    #pragma unroll
    for (int n = 0; n < 2; ++n)
      #pragma unroll
      for (int r = 0; r < 4; ++r) {
        int row = R0 + wm * 64 + m * 16 + lk * 4 + r;
        int col = n0 + wn * 32 + n * 16 + lr;        // h
        float a = acc[m][n][r];
        if (isQ) {
          float F  = exp2_hw(-PSCALE * a);           // e^{-2q}
          float WF = -2.f * wv[col] * F;
          float2 o = {WF, F};
          *(float2*)(QW + ((size_t)row * Hn + col) * 2) = o;
        } else {
          int krow = row - 2048;
          int bb = krow >> 7, k = krow & 127;
          float e = exp2_hw(PSCALE * a);             // e^{2k}
          Ekt[((size_t)(bb * 256 + (col >> 1)) * 128 + k) * 2 + (col & 1)] = e;
        }
      }
}

// ---------- K3: scores + masked softmax -> At bf16 ----------
// Block = (qt, b): 4 q rows, 512 threads = 8 waves (wave = 1 q row x 64 k).
// term(q,k,h) = WFq[q,h] / (Fq[q,h] + Ek[k,h]);  paired over h, 1 rcp per 2 h.
__global__ __launch_bounds__(512) void score_kernel(
    const float* __restrict__ QW, const float* __restrict__ Ekt,
    const int* __restrict__ valid_lens, unsigned short* __restrict__ At)
{
  __shared__ float EkL[8192];                        // [32 h2][128 k][2] = 32KB
  __shared__ float RedM[4][2], RedS[4][2];

  const int t = threadIdx.x;
  const int b = blockIdx.y;
  const int q0 = blockIdx.x * 4;
  const int kk = t & 127;                            // this wave's k column
  const int hf = (t >> 6) & 1;
  const int q_loc = __builtin_amdgcn_readfirstlane(t >> 7);   // wave-uniform

  const float* qw = QW + (size_t)(b * Qn + q0 + q_loc) * 1024;
  const float4* src = (const float4*)(Ekt + (size_t)b * 65536);

  float4 pr[4];
  #pragma unroll
  for (int j = 0; j < 4; ++j) pr[j] = src[t + j * 512];

  float acc = 0.f;
  for (int c = 0; c < 8; ++c) {
    __syncthreads();
    #pragma unroll
    for (int j = 0; j < 4; ++j) ((float4*)EkL)[t + j * 512] = pr[j];
    if (c < 7) {
      const float4* s2 = src + (c + 1) * 2048;
      #pragma unroll
      for (int j = 0; j < 4; ++j) pr[j] = s2[t + j * 512];
    }
    __syncthreads();

    const float* qc = qw + c * 128;
    #pragma unroll
    for (int i = 0; i < 32; ++i) {
      float4 qv = *(const float4*)(qc + 4 * i);      // s_load: {WF0,F0,WF1,F1}
      float2 ek = *(const float2*)&EkL[i * 256 + 2 * kk];
      float d0 = qv.y + ek.x;
      float d1 = qv.w + ek.y;
      float num = __builtin_fmaf(qv.x, d1, qv.z * d0);
      float dd = d0 * d1;
      acc = __builtin_fmaf(num, __builtin_amdgcn_rcpf(dd), acc);
    }
  }

  // ---- masked softmax over k: q row spans 2 waves (hf 0/1) ----
  const int vlen = valid_lens[b];
  const bool ok = kk < vlen;
  float sv = ok ? acc : NEGV;
  #pragma unroll
  for (int xm = 32; xm >= 1; xm >>= 1) sv = fmaxf(sv, __shfl_xor(sv, xm));
  if ((t & 63) == 0) RedM[q_loc][hf] = sv;
  __syncthreads();
  float m = fmaxf(RedM[q_loc][0], RedM[q_loc][1]);
  float ev = ok ? exp2_hw((acc - m) * 1.44269504f) : 0.f;
  float s = ev;
  #pragma unroll
  for (int xm = 32; xm >= 1; xm >>= 1) s += __shfl_xor(s, xm);
  if ((t & 63) == 0) RedS[q_loc][hf] = s;
  __syncthreads();
  float sum = RedS[q_loc][0] + RedS[q_loc][1];
  At[((size_t)(b * Qn) + q0 + q_loc) * Kn + kk] = f2bf(ev * __builtin_amdgcn_rcpf(sum));
}

// ---------- K4: out = At @ V via bf16 MFMA ----------
__global__ __launch_bounds__(256) void av_mfma(
    const unsigned short* __restrict__ At, const unsigned short* __restrict__ Vt,
    float* __restrict__ out)
{
  __shared__ unsigned short AtL[128][72];
  __shared__ unsigned short VL[128][72];
  const int t = threadIdx.x, w = t >> 6, l = t & 63;
  const int wm = w >> 1, wn = w & 1;
  const int dt = blockIdx.x;
  const int b = blockIdx.y;
  const int lr = l & 15, lk = l >> 4;

  f32x4 acc[4][4];
  #pragma unroll
  for (int m = 0; m < 4; ++m)
    #pragma unroll
    for (int n = 0; n < 4; ++n) acc[m][n] = (f32x4)0.f;

  const unsigned short* Atb = At + (size_t)b * Qn * Kn;
  const unsigned short* Vtb = Vt + (size_t)b * 65536 + (size_t)dt * 128 * Kn;

  for (int k0 = 0; k0 < Kn; k0 += 64) {
    ushort4 ar[4][2], vr[4][2];
    #pragma unroll
    for (int i = 0; i < 4; ++i) {
      int g = t + 256 * i, r = g >> 3, c = g & 7;
      const unsigned short* p = Atb + (size_t)r * Kn + k0 + c * 8;
      ar[i][0] = *(const ushort4*)p; ar[i][1] = *(const ushort4*)(p + 4);
      const unsigned short* pv = Vtb + (size_t)r * Kn + k0 + c * 8;
      vr[i][0] = *(const ushort4*)pv; vr[i][1] = *(const ushort4*)(pv + 4);
    }
    __syncthreads();
    #pragma unroll
    for (int i = 0; i < 4; ++i) {
      int g = t + 256 * i, r = g >> 3, c = g & 7;
      *(ushort4*)&AtL[r][c * 8] = ar[i][0]; *(ushort4*)&AtL[r][c * 8 + 4] = ar[i][1];
      *(ushort4*)&VL[r][c * 8] = vr[i][0];  *(ushort4*)&VL[r][c * 8 + 4] = vr[i][1];
    }
    __syncthreads();
    #pragma unroll
    for (int ks = 0; ks < 2; ++ks) {
      s16x8 af[4], bf_[4];
      #pragma unroll
      for (int m = 0; m < 4; ++m)
        af[m] = *(const s16x8*)&AtL[wm * 64 + m * 16 + lr][ks * 32 + lk * 8];
      #pragma unroll
      for (int n = 0; n < 4; ++n)
        bf_[n] = *(const s16x8*)&VL[wn * 64 + n * 16 + lr][ks * 32 + lk * 8];
      #pragma unroll
      for (int m = 0; m < 4; ++m)
        #pragma unroll
        for (int n = 0; n < 4; ++n)
          acc[m][n] = __builtin_amdgcn_mfma_f32_16x16x32_bf16(af[m], bf_[n], acc[m][n], 0, 0, 0);
    }
    __syncthreads();
  }

  #pragma unroll
  for (int m = 0; m < 4; ++m)
    #pragma unroll
    for (int n = 0; n < 4; ++n)
      #pragma unroll
      for (int r = 0; r < 4; ++r) {
        int row = wm * 64 + m * 16 + lk * 4 + r;
        int col = dt * 128 + wn * 64 + n * 16 + lr;
        out[((size_t)(b * Qn) + row) * Dn + col] = acc[m][n][r];
      }
}

extern "C" void kernel_launch(void* const* d_in, const int* in_sizes, int n_in,
                              void* d_out, int out_size, void* d_ws, size_t ws_size,
                              hipStream_t stream) {
  const float* queries    = (const float*)d_in[0];
  const float* keys       = (const float*)d_in[1];
  const float* values     = (const float*)d_in[2];
  const int*   valid_lens = (const int*)d_in[3];
  const float* Wq         = (const float*)d_in[4];
  const float* Wk         = (const float*)d_in[5];
  const float* wv         = (const float*)d_in[6];
  float* out = (float*)d_out;

  unsigned short* Abf = (unsigned short*)d_ws;     // 4096*512 bf16       (4MB)
  unsigned short* Wt  = Abf + 2097152;             // 2*512*512 bf16      (1MB)
  unsigned short* Vt  = Wt + 524288;               // 16*512*128 bf16     (2MB)
  float*          QW  = (float*)(Vt + 1048576);    // 2048*512*2 f32      (8MB)
  float*          Ekt = QW + 2097152;              // 16*256*128*2 f32    (4MB)
  unsigned short* At  = (unsigned short*)(Ekt + 1048576); // 16*128*128   (0.5MB)

  convert_kernel<<<768, 256, 0, stream>>>(queries, keys, Wq, Wk, values, Abf, Wt, Vt);
  proj_mfma<<<dim3(32, 8), 256, 0, stream>>>(Abf, Wt, wv, QW, Ekt);
  score_kernel<<<dim3(32, 16), 512, 0, stream>>>(QW, Ekt, valid_lens, At);
  av_mfma<<<dim3(4, 16), 256, 0, stream>>>(At, Vt, out);
}

// Round 5
// 53.972 us; speedup vs baseline: 1.5246x; 1.5246x over previous
//
#include <hip/hip_runtime.h>

#define Bn 16
#define Qn 128
#define Kn 128
#define Dn 512
#define Hn 512
#define NEGV (-3.0e38f)
// 2*log2(e): exp2(PSCALE*x) == e^{2x}
#define PSCALE 2.8853900817779268f

typedef short s16x8 __attribute__((ext_vector_type(8)));
typedef float f32x4 __attribute__((ext_vector_type(4)));

__device__ __forceinline__ float exp2_hw(float x) {
  float r;
  asm("v_exp_f32 %0, %1" : "=v"(r) : "v"(x));
  return r;
}
__device__ __forceinline__ float rcp_hw(float x) { return __builtin_amdgcn_rcpf(x); }
__device__ __forceinline__ unsigned short f2bf(float f) {   // RNE f32->bf16
  unsigned int u = __float_as_uint(f);
  u += 0x7fff + ((u >> 16) & 1);
  return (unsigned short)(u >> 16);
}

// ---------- K1: convert inputs to bf16 (A rows, W transposed, V transposed) ----------
__global__ __launch_bounds__(256) void convert_kernel(
    const float* __restrict__ queries, const float* __restrict__ keys,
    const float* __restrict__ Wq, const float* __restrict__ Wk,
    const float* __restrict__ values,
    unsigned short* __restrict__ Abf, unsigned short* __restrict__ Wt,
    unsigned short* __restrict__ Vt)
{
  const int bid = blockIdx.x, t = threadIdx.x;
  if (bid < 512) {
    const int gid = bid * 256 + t;
    const size_t base = (size_t)gid * 16;
    const float* src = (base < 1048576) ? (queries + base) : (keys + (base - 1048576));
    unsigned short o[16];
    #pragma unroll
    for (int j = 0; j < 4; ++j) {
      float4 v = *(const float4*)(src + j * 4);
      o[j * 4 + 0] = f2bf(v.x); o[j * 4 + 1] = f2bf(v.y);
      o[j * 4 + 2] = f2bf(v.z); o[j * 4 + 3] = f2bf(v.w);
    }
    #pragma unroll
    for (int j = 0; j < 4; ++j)
      *(ushort4*)(Abf + base + j * 4) = *(ushort4*)&o[j * 4];
  } else if (bid < 640) {
    const int tid = (bid - 512) * 256 + t;
    const int n = tid & 511, rest = tid >> 9;
    const int sel = rest >> 5, k16 = rest & 31;
    const float* W = sel ? Wk : Wq;
    unsigned short o[16];
    #pragma unroll
    for (int i = 0; i < 16; ++i)
      o[i] = f2bf(W[(size_t)(k16 * 16 + i) * Hn + n]);
    unsigned short* dst = Wt + (size_t)sel * 262144 + (size_t)n * 512 + k16 * 16;
    #pragma unroll
    for (int j = 0; j < 4; ++j) *(ushort4*)(dst + j * 4) = *(ushort4*)&o[j * 4];
  } else {
    const int tid = (bid - 640) * 256 + t;
    const int d = tid & 511, rest = tid >> 9;
    const int b = rest >> 2, k32 = rest & 3;
    unsigned short o[32];
    #pragma unroll
    for (int i = 0; i < 32; ++i)
      o[i] = f2bf(values[((size_t)(b * Kn + k32 * 32 + i)) * Dn + d]);
    unsigned short* dst = Vt + (size_t)b * 65536 + (size_t)d * 128 + k32 * 32;
    #pragma unroll
    for (int j = 0; j < 8; ++j) *(ushort4*)(dst + j * 4) = *(ushort4*)&o[j * 4];
  }
}

// ---------- K2: projections via bf16 MFMA ----------
// q rows -> QW[q_glob][512 h][{WF=-2*wv*e^{-2q}, F=e^{-2q}}] f32
// k rows -> Ekq[b][512 h][128 k] = e^{2k}  f32 (k-contiguous for score loads)
__global__ __launch_bounds__(256) void proj_mfma(
    const unsigned short* __restrict__ Abf, const unsigned short* __restrict__ Wt,
    const float* __restrict__ wv,
    float* __restrict__ QW, float* __restrict__ Ekq)
{
  __shared__ unsigned short Al[128][72];
  __shared__ unsigned short Bl[64][72];
  const int t = threadIdx.x, w = t >> 6, l = t & 63;
  const int wm = w >> 1, wn = w & 1;
  const int rowTile = blockIdx.x;          // 0..31
  const int n0 = blockIdx.y * 64;
  const int R0 = rowTile * 128;
  const bool isQ = rowTile < 16;
  const unsigned short* Wsel = Wt + (isQ ? 0 : 262144);

  f32x4 acc[4][2];
  #pragma unroll
  for (int m = 0; m < 4; ++m)
    #pragma unroll
    for (int n = 0; n < 2; ++n) acc[m][n] = (f32x4)0.f;

  const int lr = l & 15, lk = l >> 4;

  for (int k0 = 0; k0 < Hn; k0 += 64) {
    ushort4 ar[4][2], br[2][2];
    #pragma unroll
    for (int i = 0; i < 4; ++i) {
      int g = t + 256 * i, r = g >> 3, c = g & 7;
      const unsigned short* p = Abf + (size_t)(R0 + r) * Hn + k0 + c * 8;
      ar[i][0] = *(const ushort4*)p; ar[i][1] = *(const ushort4*)(p + 4);
    }
    #pragma unroll
    for (int i = 0; i < 2; ++i) {
      int g = t + 256 * i, r = g >> 3, c = g & 7;
      const unsigned short* p = Wsel + (size_t)(n0 + r) * Hn + k0 + c * 8;
      br[i][0] = *(const ushort4*)p; br[i][1] = *(const ushort4*)(p + 4);
    }
    __syncthreads();
    #pragma unroll
    for (int i = 0; i < 4; ++i) {
      int g = t + 256 * i, r = g >> 3, c = g & 7;
      *(ushort4*)&Al[r][c * 8] = ar[i][0]; *(ushort4*)&Al[r][c * 8 + 4] = ar[i][1];
    }
    #pragma unroll
    for (int i = 0; i < 2; ++i) {
      int g = t + 256 * i, r = g >> 3, c = g & 7;
      *(ushort4*)&Bl[r][c * 8] = br[i][0]; *(ushort4*)&Bl[r][c * 8 + 4] = br[i][1];
    }
    __syncthreads();
    #pragma unroll
    for (int ks = 0; ks < 2; ++ks) {
      s16x8 af[4], bf_[2];
      #pragma unroll
      for (int m = 0; m < 4; ++m)
        af[m] = *(const s16x8*)&Al[wm * 64 + m * 16 + lr][ks * 32 + lk * 8];
      #pragma unroll
      for (int n = 0; n < 2; ++n)
        bf_[n] = *(const s16x8*)&Bl[wn * 32 + n * 16 + lr][ks * 32 + lk * 8];
      #pragma unroll
      for (int m = 0; m < 4; ++m)
        #pragma unroll
        for (int n = 0; n < 2; ++n)
          acc[m][n] = __builtin_amdgcn_mfma_f32_16x16x32_bf16(af[m], bf_[n], acc[m][n], 0, 0, 0);
    }
    __syncthreads();
  }

  #pragma unroll
  for (int m = 0; m < 4; ++m)
    #pragma unroll
    for (int n = 0; n < 2; ++n)
      #pragma unroll
      for (int r = 0; r < 4; ++r) {
        int row = R0 + wm * 64 + m * 16 + lk * 4 + r;
        int col = n0 + wn * 32 + n * 16 + lr;        // h
        float a = acc[m][n][r];
        if (isQ) {
          float F  = exp2_hw(-PSCALE * a);           // e^{-2q}
          float WF = -2.f * wv[col] * F;
          float2 o = {WF, F};
          *(float2*)(QW + ((size_t)row * Hn + col) * 2) = o;
        } else {
          int krow = row - 2048;
          int bb = krow >> 7, k = krow & 127;
          Ekq[(size_t)bb * 65536 + (size_t)col * 128 + k] = exp2_hw(PSCALE * a);
        }
      }
}

// ---------- K3: score partials, no LDS, no barriers ----------
// Block = 256 thr = 4 waves. id -> (g = b*4+hs [XCD-grouped], qt).
// Wave covers 4 q x 128 k; lane: 1 q (l>>4), 8 k ((l&15)*8); h-quarter of 128.
// term(q,k,h) = WF[q,h] / (F[q,h] + Ek[k,h]); 2 h share one rcp.
__global__ __launch_bounds__(256) void score_kernel(
    const float* __restrict__ QW, const float* __restrict__ Ekq,
    float* __restrict__ Sp)
{
  const int id = blockIdx.x;
  const int g = id & 63, qt = id >> 6;     // siblings (same g) stride 64 = same XCD
  const int b = g >> 2, hs = g & 3;
  const int t = threadIdx.x, w = t >> 6, l = t & 63;
  const int q  = qt * 16 + w * 4 + (l >> 4);
  const int k0 = (l & 15) * 8;
  const int h0 = hs * 128;

  const float* ek  = Ekq + (size_t)b * 65536 + (size_t)h0 * 128 + k0;
  const float* qwp = QW + ((size_t)(b * Qn + q) * Hn + h0) * 2;

  float acc[8];
  #pragma unroll
  for (int j = 0; j < 8; ++j) acc[j] = 0.f;

  float4 e0a = *(const float4*)(ek);
  float4 e0b = *(const float4*)(ek + 4);
  float4 e1a = *(const float4*)(ek + 128);
  float4 e1b = *(const float4*)(ek + 132);
  float4 qv  = *(const float4*)(qwp);

  #pragma unroll 2
  for (int hb = 0; hb < 64; ++hb) {        // 2 h per iter
    float4 ce0a = e0a, ce0b = e0b, ce1a = e1a, ce1b = e1b, cqv = qv;
    if (hb < 63) {
      const float* ep = ek + (size_t)(2 * hb + 2) * 128;
      e0a = *(const float4*)(ep);
      e0b = *(const float4*)(ep + 4);
      e1a = *(const float4*)(ep + 128);
      e1b = *(const float4*)(ep + 132);
      qv  = *(const float4*)(qwp + hb * 4 + 4);
    }
    const float WF0 = cqv.x, F0 = cqv.y, WF1 = cqv.z, F1 = cqv.w;
    float d0, d1, num;
    d0 = F0 + ce0a.x; d1 = F1 + ce1a.x;
    num = __builtin_fmaf(WF0, d1, WF1 * d0);
    acc[0] = __builtin_fmaf(num, rcp_hw(d0 * d1), acc[0]);
    d0 = F0 + ce0a.y; d1 = F1 + ce1a.y;
    num = __builtin_fmaf(WF0, d1, WF1 * d0);
    acc[1] = __builtin_fmaf(num, rcp_hw(d0 * d1), acc[1]);
    d0 = F0 + ce0a.z; d1 = F1 + ce1a.z;
    num = __builtin_fmaf(WF0, d1, WF1 * d0);
    acc[2] = __builtin_fmaf(num, rcp_hw(d0 * d1), acc[2]);
    d0 = F0 + ce0a.w; d1 = F1 + ce1a.w;
    num = __builtin_fmaf(WF0, d1, WF1 * d0);
    acc[3] = __builtin_fmaf(num, rcp_hw(d0 * d1), acc[3]);
    d0 = F0 + ce0b.x; d1 = F1 + ce1b.x;
    num = __builtin_fmaf(WF0, d1, WF1 * d0);
    acc[4] = __builtin_fmaf(num, rcp_hw(d0 * d1), acc[4]);
    d0 = F0 + ce0b.y; d1 = F1 + ce1b.y;
    num = __builtin_fmaf(WF0, d1, WF1 * d0);
    acc[5] = __builtin_fmaf(num, rcp_hw(d0 * d1), acc[5]);
    d0 = F0 + ce0b.z; d1 = F1 + ce1b.z;
    num = __builtin_fmaf(WF0, d1, WF1 * d0);
    acc[6] = __builtin_fmaf(num, rcp_hw(d0 * d1), acc[6]);
    d0 = F0 + ce0b.w; d1 = F1 + ce1b.w;
    num = __builtin_fmaf(WF0, d1, WF1 * d0);
    acc[7] = __builtin_fmaf(num, rcp_hw(d0 * d1), acc[7]);
  }

  float4 o0 = {acc[0], acc[1], acc[2], acc[3]};
  float4 o1 = {acc[4], acc[5], acc[6], acc[7]};
  size_t sb = (((size_t)hs * Bn + b) * Qn + q) * Kn + k0;
  *(float4*)(Sp + sb) = o0;
  *(float4*)(Sp + sb + 4) = o1;
}

// ---------- K4: sum h-partials + masked softmax -> At bf16 ----------
// Block = (qt2, b): 16 q rows, 512 thr; thread: 1 q (t>>5), 4 k ((t&31)*4).
__global__ __launch_bounds__(512) void softmax_kernel(
    const float* __restrict__ Sp, const int* __restrict__ valid_lens,
    unsigned short* __restrict__ At)
{
  const int t = threadIdx.x;
  const int b = blockIdx.y;
  const int q = blockIdx.x * 16 + (t >> 5);
  const int k0 = (t & 31) * 4;
  const size_t base = ((size_t)b * Qn + q) * Kn + k0;

  float4 s0 = *(const float4*)(Sp + base);
  float4 s1 = *(const float4*)(Sp + base + 262144);
  float4 s2 = *(const float4*)(Sp + base + 524288);
  float4 s3 = *(const float4*)(Sp + base + 786432);
  float s[4] = {s0.x + s1.x + s2.x + s3.x, s0.y + s1.y + s2.y + s3.y,
                s0.z + s1.z + s2.z + s3.z, s0.w + s1.w + s2.w + s3.w};

  const int vlen = valid_lens[b];
  bool ok[4];
  float m = NEGV;
  #pragma unroll
  for (int j = 0; j < 4; ++j) {
    ok[j] = (k0 + j) < vlen;
    if (ok[j]) m = fmaxf(m, s[j]);
  }
  #pragma unroll
  for (int xm = 16; xm >= 1; xm >>= 1) m = fmaxf(m, __shfl_xor(m, xm, 32));
  float e[4], sum = 0.f;
  #pragma unroll
  for (int j = 0; j < 4; ++j) {
    e[j] = ok[j] ? exp2_hw((s[j] - m) * 1.44269504f) : 0.f;
    sum += e[j];
  }
  #pragma unroll
  for (int xm = 16; xm >= 1; xm >>= 1) sum += __shfl_xor(sum, xm, 32);
  float inv = rcp_hw(sum);
  ushort4 o = {f2bf(e[0] * inv), f2bf(e[1] * inv), f2bf(e[2] * inv), f2bf(e[3] * inv)};
  *(ushort4*)(At + base) = o;
}

// ---------- K5: out = At @ V via bf16 MFMA ----------
__global__ __launch_bounds__(256) void av_mfma(
    const unsigned short* __restrict__ At, const unsigned short* __restrict__ Vt,
    float* __restrict__ out)
{
  __shared__ unsigned short AtL[128][72];
  __shared__ unsigned short VL[128][72];
  const int t = threadIdx.x, w = t >> 6, l = t & 63;
  const int wm = w >> 1, wn = w & 1;
  const int dt = blockIdx.x;
  const int b = blockIdx.y;
  const int lr = l & 15, lk = l >> 4;

  f32x4 acc[4][4];
  #pragma unroll
  for (int m = 0; m < 4; ++m)
    #pragma unroll
    for (int n = 0; n < 4; ++n) acc[m][n] = (f32x4)0.f;

  const unsigned short* Atb = At + (size_t)b * Qn * Kn;
  const unsigned short* Vtb = Vt + (size_t)b * 65536 + (size_t)dt * 128 * Kn;

  for (int k0 = 0; k0 < Kn; k0 += 64) {
    ushort4 ar[4][2], vr[4][2];
    #pragma unroll
    for (int i = 0; i < 4; ++i) {
      int g = t + 256 * i, r = g >> 3, c = g & 7;
      const unsigned short* p = Atb + (size_t)r * Kn + k0 + c * 8;
      ar[i][0] = *(const ushort4*)p; ar[i][1] = *(const ushort4*)(p + 4);
      const unsigned short* pv = Vtb + (size_t)r * Kn + k0 + c * 8;
      vr[i][0] = *(const ushort4*)pv; vr[i][1] = *(const ushort4*)(pv + 4);
    }
    __syncthreads();
    #pragma unroll
    for (int i = 0; i < 4; ++i) {
      int g = t + 256 * i, r = g >> 3, c = g & 7;
      *(ushort4*)&AtL[r][c * 8] = ar[i][0]; *(ushort4*)&AtL[r][c * 8 + 4] = ar[i][1];
      *(ushort4*)&VL[r][c * 8] = vr[i][0];  *(ushort4*)&VL[r][c * 8 + 4] = vr[i][1];
    }
    __syncthreads();
    #pragma unroll
    for (int ks = 0; ks < 2; ++ks) {
      s16x8 af[4], bf_[4];
      #pragma unroll
      for (int m = 0; m < 4; ++m)
        af[m] = *(const s16x8*)&AtL[wm * 64 + m * 16 + lr][ks * 32 + lk * 8];
      #pragma unroll
      for (int n = 0; n < 4; ++n)
        bf_[n] = *(const s16x8*)&VL[wn * 64 + n * 16 + lr][ks * 32 + lk * 8];
      #pragma unroll
      for (int m = 0; m < 4; ++m)
        #pragma unroll
        for (int n = 0; n < 4; ++n)
          acc[m][n] = __builtin_amdgcn_mfma_f32_16x16x32_bf16(af[m], bf_[n], acc[m][n], 0, 0, 0);
    }
    __syncthreads();
  }

  #pragma unroll
  for (int m = 0; m < 4; ++m)
    #pragma unroll
    for (int n = 0; n < 4; ++n)
      #pragma unroll
      for (int r = 0; r < 4; ++r) {
        int row = wm * 64 + m * 16 + lk * 4 + r;
        int col = dt * 128 + wn * 64 + n * 16 + lr;
        out[((size_t)(b * Qn) + row) * Dn + col] = acc[m][n][r];
      }
}

extern "C" void kernel_launch(void* const* d_in, const int* in_sizes, int n_in,
                              void* d_out, int out_size, void* d_ws, size_t ws_size,
                              hipStream_t stream) {
  const float* queries    = (const float*)d_in[0];
  const float* keys       = (const float*)d_in[1];
  const float* values     = (const float*)d_in[2];
  const int*   valid_lens = (const int*)d_in[3];
  const float* Wq         = (const float*)d_in[4];
  const float* Wk         = (const float*)d_in[5];
  const float* wv         = (const float*)d_in[6];
  float* out = (float*)d_out;

  unsigned short* Abf = (unsigned short*)d_ws;     // 4096*512 bf16       (4MB)
  unsigned short* Wt  = Abf + 2097152;             // 2*512*512 bf16      (1MB)
  unsigned short* Vt  = Wt + 524288;               // 16*512*128 bf16     (2MB)
  float*          QW  = (float*)(Vt + 1048576);    // 2048*512*2 f32      (8MB)
  float*          Ekq = QW + 2097152;              // 16*512*128 f32      (4MB)
  float*          Sp  = Ekq + 1048576;             // 4*16*128*128 f32    (4MB)
  unsigned short* At  = (unsigned short*)(Sp + 1048576); // 16*128*128    (0.5MB)

  convert_kernel<<<768, 256, 0, stream>>>(queries, keys, Wq, Wk, values, Abf, Wt, Vt);
  proj_mfma<<<dim3(32, 8), 256, 0, stream>>>(Abf, Wt, wv, QW, Ekq);
  score_kernel<<<512, 256, 0, stream>>>(QW, Ekq, Sp);
  softmax_kernel<<<dim3(8, 16), 512, 0, stream>>>(Sp, valid_lens, At);
  av_mfma<<<dim3(4, 16), 256, 0, stream>>>(At, Vt, out);
}